// Round 3
// baseline (347.179 us; speedup 1.0000x reference)
//
#include <hip/hip_runtime.h>
#include <hip/hip_bf16.h>

#define NN 8192
#define NE 262144

typedef __attribute__((ext_vector_type(8))) short bf16x8;
typedef __attribute__((ext_vector_type(4))) float f32x4;
typedef __attribute__((ext_vector_type(16))) float f32x16;
typedef unsigned short u16;
typedef __attribute__((ext_vector_type(4))) u16 u16x4;

__device__ inline u16 f2b(float f) {
  unsigned u = __float_as_uint(f);
  unsigned r = u + 0x7FFF + ((u >> 16) & 1);   // RNE to bf16
  return (u16)(r >> 16);
}
__device__ inline float b2f(u16 b) {
  return __uint_as_float(((unsigned)b) << 16);
}

// ---------- converts ----------
// x [NN][512] f32 -> hi/lo bf16, vectorized 4/thread
__global__ void split_x(const float* __restrict__ in, u16* __restrict__ hi,
                        u16* __restrict__ lo) {
  int i = (blockIdx.x * blockDim.x + threadIdx.x) * 4;
  f32x4 v = *(const f32x4*)(in + i);
  u16x4 vh, vl;
#pragma unroll
  for (int j = 0; j < 4; ++j) {
    u16 h = f2b(v[j]);
    vh[j] = h;
    vl[j] = f2b(v[j] - b2f(h));
  }
  *(u16x4*)(hi + i) = vh;
  *(u16x4*)(lo + i) = vl;
}

// W1 [512][256] row-major -> col-major [256][512] hi/lo
__global__ void splitT_w1(const float* __restrict__ in, u16* __restrict__ hi,
                          u16* __restrict__ lo) {
  int i = blockIdx.x * blockDim.x + threadIdx.x;  // 512*256
  int k = i >> 8, n = i & 255;
  float v = in[i];
  u16 h = f2b(v);
  hi[(size_t)n * 512 + k] = h;
  lo[(size_t)n * 512 + k] = f2b(v - b2f(h));
}

// W23 col-major [256 cols][256 k]: col j<128 = W2[:,j], j>=128 = W3[:,j-128]
__global__ void build_w23T(const float* __restrict__ W2, const float* __restrict__ W3,
                           u16* __restrict__ hi, u16* __restrict__ lo) {
  int i = blockIdx.x * blockDim.x + threadIdx.x;  // 65536
  int k = i >> 8, j = i & 255;
  float v = (j < 128) ? W2[(k << 7) + j] : W3[(k << 7) + (j - 128)];
  u16 h = f2b(v);
  hi[(size_t)j * 256 + k] = h;
  lo[(size_t)j * 256 + k] = f2b(v - b2f(h));
}

// ---------- CSR build ----------
__global__ void hist_kernel(const int* __restrict__ dst, int* __restrict__ deg) {
  int i = blockIdx.x * blockDim.x + threadIdx.x;
  if (i < NE) atomicAdd(&deg[dst[i]], 1);
}

__global__ void scan_kernel(const int* __restrict__ deg, int* __restrict__ rowptr,
                            int* __restrict__ cursor) {
  __shared__ int sums[1024];
  int t = threadIdx.x;
  int loc[8];
  int s = 0;
#pragma unroll
  for (int j = 0; j < 8; ++j) { s += deg[t * 8 + j]; loc[j] = s; }
  sums[t] = s;
  __syncthreads();
  for (int off = 1; off < 1024; off <<= 1) {
    int v = (t >= off) ? sums[t - off] : 0;
    __syncthreads();
    sums[t] += v;
    __syncthreads();
  }
  int base = (t > 0) ? sums[t - 1] : 0;
  if (t == 0) rowptr[0] = 0;
#pragma unroll
  for (int j = 0; j < 8; ++j) {
    rowptr[t * 8 + j + 1] = base + loc[j];
    cursor[t * 8 + j] = base + (j ? loc[j - 1] : 0);
  }
}

__global__ void scatter_kernel(const int* __restrict__ src, const int* __restrict__ dst,
                               const float* __restrict__ w, int* cursor,
                               int* __restrict__ csr_src, float* __restrict__ csr_w) {
  int i = blockIdx.x * blockDim.x + threadIdx.x;
  if (i >= NE) return;
  int d = dst[i];
  int p = atomicAdd(&cursor[d], 1);
  csr_src[p] = src[i];
  csr_w[p] = w[i];
}

// ---------- split GEMM, bf16-hi output: C = A(MxK)@B(KxN); B packed col-major ----
// block 256 / 4 waves; wave = 16 rows x 64 cols; grid (M/64, N/64)
__global__ void gemm_split_kernel(const u16* __restrict__ Ah, const u16* __restrict__ Al,
                                  const u16* __restrict__ Bh, const u16* __restrict__ Bl,
                                  u16* __restrict__ C, int M, int N, int K) {
  int wave = threadIdx.x >> 6, lane = threadIdx.x & 63;
  int r = lane & 15, kf = (lane >> 4) * 8;
  int row = blockIdx.x * 64 + wave * 16 + r;
  int col0 = blockIdx.y * 64;
  f32x4 acc[4] = {};
  for (int k0 = 0; k0 < K; k0 += 32) {
    int ka = k0 + kf;
    bf16x8 ah = *(const bf16x8*)(Ah + (size_t)row * K + ka);
    bf16x8 al = *(const bf16x8*)(Al + (size_t)row * K + ka);
#pragma unroll
    for (int t = 0; t < 4; ++t) {
      int col = col0 + t * 16 + r;
      bf16x8 bh = *(const bf16x8*)(Bh + (size_t)col * K + ka);
      bf16x8 bl = *(const bf16x8*)(Bl + (size_t)col * K + ka);
      acc[t] = __builtin_amdgcn_mfma_f32_16x16x32_bf16(ah, bh, acc[t], 0, 0, 0);
      acc[t] = __builtin_amdgcn_mfma_f32_16x16x32_bf16(al, bh, acc[t], 0, 0, 0);
      acc[t] = __builtin_amdgcn_mfma_f32_16x16x32_bf16(ah, bl, acc[t], 0, 0, 0);
    }
  }
  int orow = blockIdx.x * 64 + wave * 16 + (lane >> 4) * 4;
#pragma unroll
  for (int t = 0; t < 4; ++t)
#pragma unroll
    for (int q = 0; q < 4; ++q)
      C[(size_t)(orow + q) * N + col0 + t * 16 + r] = f2b(acc[t][q]);
}

// ---------- spmm (CSR): 4 nodes/block, 64 lanes/node, bf16x4 gather ----------
__global__ void spmm_relu_kernel(const int* __restrict__ rowptr, const int* __restrict__ csr_src,
                                 const float* __restrict__ csr_w, const u16* __restrict__ h,
                                 u16* __restrict__ oh, u16* __restrict__ ol) {
  int n = blockIdx.x * 4 + (threadIdx.x >> 6);
  int c = (threadIdx.x & 63) * 4;
  int e0 = rowptr[n], e1 = rowptr[n + 1];
  f32x4 acc = {};
  int i = e0;
  for (; i + 2 <= e1; i += 2) {
    int s0 = csr_src[i], s1 = csr_src[i + 1];
    float w0 = csr_w[i], w1 = csr_w[i + 1];
    u16x4 v0 = *(const u16x4*)(h + (size_t)s0 * 256 + c);
    u16x4 v1 = *(const u16x4*)(h + (size_t)s1 * 256 + c);
#pragma unroll
    for (int j = 0; j < 4; ++j)
      acc[j] = fmaf(w1, b2f(v1[j]), fmaf(w0, b2f(v0[j]), acc[j]));
  }
  if (i < e1) {
    float w0 = csr_w[i];
    u16x4 v0 = *(const u16x4*)(h + (size_t)csr_src[i] * 256 + c);
#pragma unroll
    for (int j = 0; j < 4; ++j) acc[j] = fmaf(w0, b2f(v0[j]), acc[j]);
  }
  u16x4 vh, vl;
#pragma unroll
  for (int j = 0; j < 4; ++j) {
    float a = fmaxf(acc[j], 0.f);
    u16 hb = f2b(a);
    vh[j] = hb;
    vl[j] = f2b(a - b2f(hb));
  }
  *(u16x4*)(oh + (size_t)n * 256 + c) = vh;
  *(u16x4*)(ol + (size_t)n * 256 + c) = vl;
}

__global__ void spmm_out_kernel(const int* __restrict__ rowptr, const int* __restrict__ csr_src,
                                const float* __restrict__ csr_w, const u16* __restrict__ h,
                                float* __restrict__ mu, float* __restrict__ logvar,
                                float* __restrict__ z, u16* __restrict__ zh,
                                u16* __restrict__ zl) {
  int n = blockIdx.x * 4 + (threadIdx.x >> 6);
  int c = (threadIdx.x & 63) * 4;
  int e0 = rowptr[n], e1 = rowptr[n + 1];
  f32x4 acc = {};
  int i = e0;
  for (; i + 2 <= e1; i += 2) {
    int s0 = csr_src[i], s1 = csr_src[i + 1];
    float w0 = csr_w[i], w1 = csr_w[i + 1];
    u16x4 v0 = *(const u16x4*)(h + (size_t)s0 * 256 + c);
    u16x4 v1 = *(const u16x4*)(h + (size_t)s1 * 256 + c);
#pragma unroll
    for (int j = 0; j < 4; ++j)
      acc[j] = fmaf(w1, b2f(v1[j]), fmaf(w0, b2f(v0[j]), acc[j]));
  }
  if (i < e1) {
    float w0 = csr_w[i];
    u16x4 v0 = *(const u16x4*)(h + (size_t)csr_src[i] * 256 + c);
#pragma unroll
    for (int j = 0; j < 4; ++j) acc[j] = fmaf(w0, b2f(v0[j]), acc[j]);
  }
  if (c < 128) {
    *(f32x4*)(mu + (size_t)n * 128 + c) = acc;
    *(f32x4*)(z + (size_t)n * 128 + c) = acc;
    u16x4 vh, vl;
#pragma unroll
    for (int j = 0; j < 4; ++j) {
      u16 hb = f2b(acc[j]);
      vh[j] = hb;
      vl[j] = f2b(acc[j] - b2f(hb));
    }
    *(u16x4*)(zh + (size_t)n * 128 + c) = vh;
    *(u16x4*)(zl + (size_t)n * 128 + c) = vl;
  } else {
    *(f32x4*)(logvar + (size_t)n * 128 + (c - 128)) = acc;
  }
}

// ---------- adj = Z @ Z^T, split z (hi/lo), LDS-staged float4 stores ----------
// block 256 / 4 waves; block tile 128x64; wave = 32 rows x 64 cols; grid (64,128)
__global__ void zzt_kernel(const u16* __restrict__ Zh, const u16* __restrict__ Zl,
                           float* __restrict__ C) {
  __shared__ float tile[128 * 64];
  int wave = threadIdx.x >> 6, lane = threadIdx.x & 63;
  int lrow = lane & 31, lk = (lane >> 5) * 8;
  int i0 = blockIdx.x * 128 + wave * 32;
  int j0 = blockIdx.y * 64;
  f32x16 acc0 = {}, acc1 = {};
#pragma unroll
  for (int k0 = 0; k0 < 128; k0 += 16) {
    bf16x8 ah = *(const bf16x8*)(Zh + (size_t)(i0 + lrow) * 128 + k0 + lk);
    bf16x8 al = *(const bf16x8*)(Zl + (size_t)(i0 + lrow) * 128 + k0 + lk);
    bf16x8 b0h = *(const bf16x8*)(Zh + (size_t)(j0 + lrow) * 128 + k0 + lk);
    bf16x8 b0l = *(const bf16x8*)(Zl + (size_t)(j0 + lrow) * 128 + k0 + lk);
    bf16x8 b1h = *(const bf16x8*)(Zh + (size_t)(j0 + 32 + lrow) * 128 + k0 + lk);
    bf16x8 b1l = *(const bf16x8*)(Zl + (size_t)(j0 + 32 + lrow) * 128 + k0 + lk);
    acc0 = __builtin_amdgcn_mfma_f32_32x32x16_bf16(ah, b0h, acc0, 0, 0, 0);
    acc0 = __builtin_amdgcn_mfma_f32_32x32x16_bf16(ah, b0l, acc0, 0, 0, 0);
    acc0 = __builtin_amdgcn_mfma_f32_32x32x16_bf16(al, b0h, acc0, 0, 0, 0);
    acc1 = __builtin_amdgcn_mfma_f32_32x32x16_bf16(ah, b1h, acc1, 0, 0, 0);
    acc1 = __builtin_amdgcn_mfma_f32_32x32x16_bf16(ah, b1l, acc1, 0, 0, 0);
    acc1 = __builtin_amdgcn_mfma_f32_32x32x16_bf16(al, b1h, acc1, 0, 0, 0);
  }
  int rbase = wave * 32 + 4 * (lane >> 5);
  int col = lane & 31;
#pragma unroll
  for (int reg = 0; reg < 16; ++reg) {
    int rr = rbase + (reg & 3) + 8 * (reg >> 2);
    tile[rr * 64 + col] = acc0[reg];
    tile[rr * 64 + 32 + col] = acc1[reg];
  }
  __syncthreads();
  int r = threadIdx.x >> 4;          // 0..15
  int c4 = (threadIdx.x & 15) * 4;   // 0..60
#pragma unroll
  for (int p = 0; p < 8; ++p) {
    int rr = p * 16 + r;
    f32x4 v = *(const f32x4*)&tile[rr * 64 + c4];
    *(f32x4*)&C[(size_t)(blockIdx.x * 128 + rr) * NN + j0 + c4] = v;
  }
}

extern "C" void kernel_launch(void* const* d_in, const int* in_sizes, int n_in,
                              void* d_out, int out_size, void* d_ws, size_t ws_size,
                              hipStream_t stream) {
  const float* x  = (const float*)d_in[0];
  const int*   ei = (const int*)d_in[1];
  const float* ew = (const float*)d_in[2];
  const float* W1 = (const float*)d_in[3];
  const float* W2 = (const float*)d_in[4];
  const float* W3 = (const float*)d_in[5];

  float* out    = (float*)d_out;
  float* adj    = out;                                   // [8192,8192]
  float* mu     = out + (size_t)NN * NN;                 // [8192,128]
  float* logv   = mu + (size_t)NN * 128;                 // [8192,128]
  float* z      = logv + (size_t)NN * 128;               // [8192,128]

  const int* srcp = ei;
  const int* dstp = ei + NE;

  char* ws = (char*)d_ws;
  size_t off = 0;
  auto alloc = [&](size_t b) -> void* {
    void* p = ws + off;
    off = (off + b + 255) & ~(size_t)255;
    return p;
  };
  u16* xh   = (u16*)alloc((size_t)NN * 512 * 2);
  u16* xl   = (u16*)alloc((size_t)NN * 512 * 2);
  u16* W1h  = (u16*)alloc(512 * 256 * 2);   // col-major [256][512]
  u16* W1l  = (u16*)alloc(512 * 256 * 2);
  u16* W23h = (u16*)alloc(256 * 256 * 2);   // col-major [256][256]
  u16* W23l = (u16*)alloc(256 * 256 * 2);
  u16* h0   = (u16*)alloc((size_t)NN * 256 * 2);   // bf16 hi only
  u16* h1h  = (u16*)alloc((size_t)NN * 256 * 2);
  u16* h1l  = (u16*)alloc((size_t)NN * 256 * 2);
  u16* H2   = (u16*)alloc((size_t)NN * 256 * 2);   // bf16 hi only
  u16* zh   = (u16*)alloc((size_t)NN * 128 * 2);
  u16* zl   = (u16*)alloc((size_t)NN * 128 * 2);
  int* deg      = (int*)alloc(NN * 4);
  int* rowptr   = (int*)alloc((NN + 1) * 4);
  int* cursor   = (int*)alloc(NN * 4);
  int* csr_src  = (int*)alloc((size_t)NE * 4);
  float* csr_w  = (float*)alloc((size_t)NE * 4);

  hipMemsetAsync(deg, 0, NN * 4, stream);

  // converts
  split_x<<<(NN * 512 / 4) / 256, 256, 0, stream>>>(x, xh, xl);
  splitT_w1<<<(512 * 256) / 256, 256, 0, stream>>>(W1, W1h, W1l);
  build_w23T<<<(256 * 256) / 256, 256, 0, stream>>>(W2, W3, W23h, W23l);

  // CSR build
  hist_kernel<<<NE / 256, 256, 0, stream>>>(dstp, deg);
  scan_kernel<<<1, 1024, 0, stream>>>(deg, rowptr, cursor);
  scatter_kernel<<<NE / 256, 256, 0, stream>>>(srcp, dstp, ew, cursor, csr_src, csr_w);

  // h0 = bf16(x @ W1)
  gemm_split_kernel<<<dim3(NN / 64, 256 / 64), 256, 0, stream>>>(xh, xl, W1h, W1l, h0,
                                                                 NN, 256, 512);
  // h1 = relu(spmm(h0)) -> split hi/lo
  spmm_relu_kernel<<<NN / 4, 256, 0, stream>>>(rowptr, csr_src, csr_w, h0, h1h, h1l);
  // H2 = bf16(h1 @ [W2|W3])
  gemm_split_kernel<<<dim3(NN / 64, 256 / 64), 256, 0, stream>>>(h1h, h1l, W23h, W23l, H2,
                                                                 NN, 256, 256);
  // mu/logvar = spmm(H2); z = mu; zh/zl = split(mu)
  spmm_out_kernel<<<NN / 4, 256, 0, stream>>>(rowptr, csr_src, csr_w, H2, mu, logv, z,
                                              zh, zl);
  // adj = z @ z^T (split precision)
  zzt_kernel<<<dim3(NN / 128, NN / 64), 256, 0, stream>>>(zh, zl, adj);
}

// Round 4
// 280.473 us; speedup vs baseline: 1.2378x; 1.2378x over previous
//
#include <hip/hip_runtime.h>
#include <hip/hip_bf16.h>

#define NN 8192
#define NE 262144

typedef __attribute__((ext_vector_type(8))) short bf16x8;
typedef __attribute__((ext_vector_type(4))) float f32x4;
typedef __attribute__((ext_vector_type(16))) float f32x16;
typedef unsigned short u16;
typedef __attribute__((ext_vector_type(4))) u16 u16x4;

__device__ inline u16 f2b(float f) {
  unsigned u = __float_as_uint(f);
  unsigned r = u + 0x7FFF + ((u >> 16) & 1);   // RNE to bf16
  return (u16)(r >> 16);
}
__device__ inline float b2f(u16 b) {
  return __uint_as_float(((unsigned)b) << 16);
}

// ---------- converts ----------
__global__ void split_x(const float* __restrict__ in, u16* __restrict__ hi,
                        u16* __restrict__ lo) {
  int i = (blockIdx.x * blockDim.x + threadIdx.x) * 4;
  f32x4 v = *(const f32x4*)(in + i);
  u16x4 vh, vl;
#pragma unroll
  for (int j = 0; j < 4; ++j) {
    u16 h = f2b(v[j]);
    vh[j] = h;
    vl[j] = f2b(v[j] - b2f(h));
  }
  *(u16x4*)(hi + i) = vh;
  *(u16x4*)(lo + i) = vl;
}

// W1 [512][256] row-major -> col-major [256][512] hi/lo
__global__ void splitT_w1(const float* __restrict__ in, u16* __restrict__ hi,
                          u16* __restrict__ lo) {
  int i = blockIdx.x * blockDim.x + threadIdx.x;  // 512*256
  int k = i >> 8, n = i & 255;
  float v = in[i];
  u16 h = f2b(v);
  hi[(size_t)n * 512 + k] = h;
  lo[(size_t)n * 512 + k] = f2b(v - b2f(h));
}

// W23 col-major [256 cols][256 k]: col j<128 = W2[:,j], j>=128 = W3[:,j-128]
__global__ void build_w23T(const float* __restrict__ W2, const float* __restrict__ W3,
                           u16* __restrict__ hi, u16* __restrict__ lo) {
  int i = blockIdx.x * blockDim.x + threadIdx.x;  // 65536
  int k = i >> 8, j = i & 255;
  float v = (j < 128) ? W2[(k << 7) + j] : W3[(k << 7) + (j - 128)];
  u16 h = f2b(v);
  hi[(size_t)j * 256 + k] = h;
  lo[(size_t)j * 256 + k] = f2b(v - b2f(h));
}

// ---------- CSR build ----------
__global__ void hist_kernel(const int* __restrict__ dst, int* __restrict__ deg) {
  int i = blockIdx.x * blockDim.x + threadIdx.x;
  if (i < NE) atomicAdd(&deg[dst[i]], 1);
}

__global__ void scan_kernel(const int* __restrict__ deg, int* __restrict__ rowptr,
                            int* __restrict__ cursor) {
  __shared__ int sums[1024];
  int t = threadIdx.x;
  int loc[8];
  int s = 0;
#pragma unroll
  for (int j = 0; j < 8; ++j) { s += deg[t * 8 + j]; loc[j] = s; }
  sums[t] = s;
  __syncthreads();
  for (int off = 1; off < 1024; off <<= 1) {
    int v = (t >= off) ? sums[t - off] : 0;
    __syncthreads();
    sums[t] += v;
    __syncthreads();
  }
  int base = (t > 0) ? sums[t - 1] : 0;
  if (t == 0) rowptr[0] = 0;
#pragma unroll
  for (int j = 0; j < 8; ++j) {
    rowptr[t * 8 + j + 1] = base + loc[j];
    cursor[t * 8 + j] = base + (j ? loc[j - 1] : 0);
  }
}

__global__ void scatter_kernel(const int* __restrict__ src, const int* __restrict__ dst,
                               const float* __restrict__ w, int* cursor,
                               int* __restrict__ csr_src, float* __restrict__ csr_w) {
  int i = blockIdx.x * blockDim.x + threadIdx.x;
  if (i >= NE) return;
  int d = dst[i];
  int p = atomicAdd(&cursor[d], 1);
  csr_src[p] = src[i];
  csr_w[p] = w[i];
}

// ---------- split GEMM: C = A(MxK)@B(KxN) f32 out; B packed col-major ----------
// block 256 / 4 waves; wave = 16 rows x 64 cols; grid (M/64, N/64)
__global__ void gemm_split_kernel(const u16* __restrict__ Ah, const u16* __restrict__ Al,
                                  const u16* __restrict__ Bh, const u16* __restrict__ Bl,
                                  float* __restrict__ C, int M, int N, int K) {
  int wave = threadIdx.x >> 6, lane = threadIdx.x & 63;
  int r = lane & 15, kf = (lane >> 4) * 8;
  int row = blockIdx.x * 64 + wave * 16 + r;
  int col0 = blockIdx.y * 64;
  f32x4 acc[4] = {};
  for (int k0 = 0; k0 < K; k0 += 32) {
    int ka = k0 + kf;
    bf16x8 ah = *(const bf16x8*)(Ah + (size_t)row * K + ka);
    bf16x8 al = *(const bf16x8*)(Al + (size_t)row * K + ka);
#pragma unroll
    for (int t = 0; t < 4; ++t) {
      int col = col0 + t * 16 + r;
      bf16x8 bh = *(const bf16x8*)(Bh + (size_t)col * K + ka);
      bf16x8 bl = *(const bf16x8*)(Bl + (size_t)col * K + ka);
      acc[t] = __builtin_amdgcn_mfma_f32_16x16x32_bf16(ah, bh, acc[t], 0, 0, 0);
      acc[t] = __builtin_amdgcn_mfma_f32_16x16x32_bf16(al, bh, acc[t], 0, 0, 0);
      acc[t] = __builtin_amdgcn_mfma_f32_16x16x32_bf16(ah, bl, acc[t], 0, 0, 0);
    }
  }
  int orow = blockIdx.x * 64 + wave * 16 + (lane >> 4) * 4;
#pragma unroll
  for (int t = 0; t < 4; ++t)
#pragma unroll
    for (int q = 0; q < 4; ++q)
      C[(size_t)(orow + q) * N + col0 + t * 16 + r] = acc[t][q];
}

// ---------- spmm (CSR): 4 nodes/block, 64 lanes/node, float4 gather ----------
__global__ void spmm_relu_kernel(const int* __restrict__ rowptr, const int* __restrict__ csr_src,
                                 const float* __restrict__ csr_w, const float* __restrict__ h,
                                 u16* __restrict__ oh, u16* __restrict__ ol) {
  int n = blockIdx.x * 4 + (threadIdx.x >> 6);
  int c = (threadIdx.x & 63) * 4;
  int e0 = rowptr[n], e1 = rowptr[n + 1];
  f32x4 acc = {};
  int i = e0;
  for (; i + 2 <= e1; i += 2) {
    int s0 = csr_src[i], s1 = csr_src[i + 1];
    float w0 = csr_w[i], w1 = csr_w[i + 1];
    f32x4 v0 = *(const f32x4*)(h + (size_t)s0 * 256 + c);
    f32x4 v1 = *(const f32x4*)(h + (size_t)s1 * 256 + c);
#pragma unroll
    for (int j = 0; j < 4; ++j)
      acc[j] = fmaf(w1, v1[j], fmaf(w0, v0[j], acc[j]));
  }
  if (i < e1) {
    float w0 = csr_w[i];
    f32x4 v0 = *(const f32x4*)(h + (size_t)csr_src[i] * 256 + c);
#pragma unroll
    for (int j = 0; j < 4; ++j) acc[j] = fmaf(w0, v0[j], acc[j]);
  }
  u16x4 vh, vl;
#pragma unroll
  for (int j = 0; j < 4; ++j) {
    float a = fmaxf(acc[j], 0.f);
    u16 hb = f2b(a);
    vh[j] = hb;
    vl[j] = f2b(a - b2f(hb));
  }
  *(u16x4*)(oh + (size_t)n * 256 + c) = vh;
  *(u16x4*)(ol + (size_t)n * 256 + c) = vl;
}

__global__ void spmm_out_kernel(const int* __restrict__ rowptr, const int* __restrict__ csr_src,
                                const float* __restrict__ csr_w, const float* __restrict__ h,
                                float* __restrict__ mu, float* __restrict__ logvar,
                                float* __restrict__ z, u16* __restrict__ zb) {
  int n = blockIdx.x * 4 + (threadIdx.x >> 6);
  int c = (threadIdx.x & 63) * 4;
  int e0 = rowptr[n], e1 = rowptr[n + 1];
  f32x4 acc = {};
  int i = e0;
  for (; i + 2 <= e1; i += 2) {
    int s0 = csr_src[i], s1 = csr_src[i + 1];
    float w0 = csr_w[i], w1 = csr_w[i + 1];
    f32x4 v0 = *(const f32x4*)(h + (size_t)s0 * 256 + c);
    f32x4 v1 = *(const f32x4*)(h + (size_t)s1 * 256 + c);
#pragma unroll
    for (int j = 0; j < 4; ++j)
      acc[j] = fmaf(w1, v1[j], fmaf(w0, v0[j], acc[j]));
  }
  if (i < e1) {
    float w0 = csr_w[i];
    f32x4 v0 = *(const f32x4*)(h + (size_t)csr_src[i] * 256 + c);
#pragma unroll
    for (int j = 0; j < 4; ++j) acc[j] = fmaf(w0, v0[j], acc[j]);
  }
  if (c < 128) {
    *(f32x4*)(mu + (size_t)n * 128 + c) = acc;
    *(f32x4*)(z + (size_t)n * 128 + c) = acc;
    u16x4 vb;
#pragma unroll
    for (int j = 0; j < 4; ++j) vb[j] = f2b(acc[j]);
    *(u16x4*)(zb + (size_t)n * 128 + c) = vb;
  } else {
    *(f32x4*)(logvar + (size_t)n * 128 + (c - 128)) = acc;
  }
}

// ---------- adj = Z @ Z^T, Z [8192][128] bf16 ----------
// block 256 / 4 waves; tile 128 rows x 64 cols; wave = 32x64; COLUMN-FAST grid:
// grid = (NN/64 cols, NN/128 rows) so consecutive blocks fill one contiguous
// 4MB row-stripe of C (DRAM-friendly write stream). LDS-staged f32x4 stores.
__global__ void zzt_kernel(const u16* __restrict__ Z, float* __restrict__ C) {
  __shared__ float tile[128 * 64];
  int wave = threadIdx.x >> 6, lane = threadIdx.x & 63;
  int lrow = lane & 31, lk = (lane >> 5) * 8;
  int i0 = blockIdx.y * 128 + wave * 32;
  int j0 = blockIdx.x * 64;
  f32x16 acc0 = {}, acc1 = {};
#pragma unroll
  for (int k0 = 0; k0 < 128; k0 += 16) {
    bf16x8 a  = *(const bf16x8*)(Z + (size_t)(i0 + lrow) * 128 + k0 + lk);
    bf16x8 b0 = *(const bf16x8*)(Z + (size_t)(j0 + lrow) * 128 + k0 + lk);
    bf16x8 b1 = *(const bf16x8*)(Z + (size_t)(j0 + 32 + lrow) * 128 + k0 + lk);
    acc0 = __builtin_amdgcn_mfma_f32_32x32x16_bf16(a, b0, acc0, 0, 0, 0);
    acc1 = __builtin_amdgcn_mfma_f32_32x32x16_bf16(a, b1, acc1, 0, 0, 0);
  }
  int rbase = wave * 32 + 4 * (lane >> 5);
  int col = lane & 31;
#pragma unroll
  for (int reg = 0; reg < 16; ++reg) {
    int rr = rbase + (reg & 3) + 8 * (reg >> 2);
    tile[rr * 64 + col] = acc0[reg];
    tile[rr * 64 + 32 + col] = acc1[reg];
  }
  __syncthreads();
  int r = threadIdx.x >> 4;          // 0..15
  int c4 = (threadIdx.x & 15) * 4;   // 0..60
#pragma unroll
  for (int p = 0; p < 8; ++p) {
    int rr = p * 16 + r;
    f32x4 v = *(const f32x4*)&tile[rr * 64 + c4];
    *(f32x4*)&C[(size_t)(blockIdx.y * 128 + rr) * NN + j0 + c4] = v;
  }
}

extern "C" void kernel_launch(void* const* d_in, const int* in_sizes, int n_in,
                              void* d_out, int out_size, void* d_ws, size_t ws_size,
                              hipStream_t stream) {
  const float* x  = (const float*)d_in[0];
  const int*   ei = (const int*)d_in[1];
  const float* ew = (const float*)d_in[2];
  const float* W1 = (const float*)d_in[3];
  const float* W2 = (const float*)d_in[4];
  const float* W3 = (const float*)d_in[5];

  float* out    = (float*)d_out;
  float* adj    = out;                                   // [8192,8192]
  float* mu     = out + (size_t)NN * NN;                 // [8192,128]
  float* logv   = mu + (size_t)NN * 128;                 // [8192,128]
  float* z      = logv + (size_t)NN * 128;               // [8192,128]

  const int* srcp = ei;
  const int* dstp = ei + NE;

  char* ws = (char*)d_ws;
  size_t off = 0;
  auto alloc = [&](size_t b) -> void* {
    void* p = ws + off;
    off = (off + b + 255) & ~(size_t)255;
    return p;
  };
  u16* xh   = (u16*)alloc((size_t)NN * 512 * 2);
  u16* xl   = (u16*)alloc((size_t)NN * 512 * 2);
  u16* W1h  = (u16*)alloc(512 * 256 * 2);   // col-major [256][512]
  u16* W1l  = (u16*)alloc(512 * 256 * 2);
  u16* W23h = (u16*)alloc(256 * 256 * 2);   // col-major [256][256]
  u16* W23l = (u16*)alloc(256 * 256 * 2);
  float* h0 = (float*)alloc((size_t)NN * 256 * 4);
  u16* h1h  = (u16*)alloc((size_t)NN * 256 * 2);
  u16* h1l  = (u16*)alloc((size_t)NN * 256 * 2);
  float* H2 = (float*)alloc((size_t)NN * 256 * 4);
  u16* zb   = (u16*)alloc((size_t)NN * 128 * 2);
  int* deg      = (int*)alloc(NN * 4);
  int* rowptr   = (int*)alloc((NN + 1) * 4);
  int* cursor   = (int*)alloc(NN * 4);
  int* csr_src  = (int*)alloc((size_t)NE * 4);
  float* csr_w  = (float*)alloc((size_t)NE * 4);

  hipMemsetAsync(deg, 0, NN * 4, stream);

  // converts
  split_x<<<(NN * 512 / 4) / 256, 256, 0, stream>>>(x, xh, xl);
  splitT_w1<<<(512 * 256) / 256, 256, 0, stream>>>(W1, W1h, W1l);
  build_w23T<<<(256 * 256) / 256, 256, 0, stream>>>(W2, W3, W23h, W23l);

  // CSR build
  hist_kernel<<<NE / 256, 256, 0, stream>>>(dstp, deg);
  scan_kernel<<<1, 1024, 0, stream>>>(deg, rowptr, cursor);
  scatter_kernel<<<NE / 256, 256, 0, stream>>>(srcp, dstp, ew, cursor, csr_src, csr_w);

  // h0 = x @ W1 (f32)
  gemm_split_kernel<<<dim3(NN / 64, 256 / 64), 256, 0, stream>>>(xh, xl, W1h, W1l, h0,
                                                                 NN, 256, 512);
  // h1 = relu(spmm(h0)) -> split hi/lo
  spmm_relu_kernel<<<NN / 4, 256, 0, stream>>>(rowptr, csr_src, csr_w, h0, h1h, h1l);
  // H2 = h1 @ [W2|W3] (f32)
  gemm_split_kernel<<<dim3(NN / 64, 256 / 64), 256, 0, stream>>>(h1h, h1l, W23h, W23l, H2,
                                                                 NN, 256, 256);
  // mu/logvar = spmm(H2); z = mu; zb = bf16(mu)
  spmm_out_kernel<<<NN / 4, 256, 0, stream>>>(rowptr, csr_src, csr_w, H2, mu, logv, z, zb);
  // adj = z @ z^T  (column-fast grid)
  zzt_kernel<<<dim3(NN / 64, NN / 128), 256, 0, stream>>>(zb, adj);
}

// Round 5
// 221.107 us; speedup vs baseline: 1.5702x; 1.2685x over previous
//
#include <hip/hip_runtime.h>
#include <hip/hip_bf16.h>

#define NN 8192
#define NE 262144

typedef __attribute__((ext_vector_type(8))) short bf16x8;
typedef __attribute__((ext_vector_type(4))) float f32x4;
typedef __attribute__((ext_vector_type(16))) float f32x16;
typedef unsigned short u16;
typedef __attribute__((ext_vector_type(4))) u16 u16x4;

__device__ inline u16 f2b(float f) {
  unsigned u = __float_as_uint(f);
  unsigned r = u + 0x7FFF + ((u >> 16) & 1);   // RNE to bf16
  return (u16)(r >> 16);
}
__device__ inline float b2f(u16 b) {
  return __uint_as_float(((unsigned)b) << 16);
}

// ---------- converts ----------
__global__ void split_x(const float* __restrict__ in, u16* __restrict__ hi,
                        u16* __restrict__ lo) {
  int i = (blockIdx.x * blockDim.x + threadIdx.x) * 4;
  f32x4 v = *(const f32x4*)(in + i);
  u16x4 vh, vl;
#pragma unroll
  for (int j = 0; j < 4; ++j) {
    u16 h = f2b(v[j]);
    vh[j] = h;
    vl[j] = f2b(v[j] - b2f(h));
  }
  *(u16x4*)(hi + i) = vh;
  *(u16x4*)(lo + i) = vl;
}

// W1 [512][256] row-major -> col-major [256][512] hi/lo
__global__ void splitT_w1(const float* __restrict__ in, u16* __restrict__ hi,
                          u16* __restrict__ lo) {
  int i = blockIdx.x * blockDim.x + threadIdx.x;  // 512*256
  int k = i >> 8, n = i & 255;
  float v = in[i];
  u16 h = f2b(v);
  hi[(size_t)n * 512 + k] = h;
  lo[(size_t)n * 512 + k] = f2b(v - b2f(h));
}

// W23 col-major [256 cols][256 k]: col j<128 = W2[:,j], j>=128 = W3[:,j-128]
__global__ void build_w23T(const float* __restrict__ W2, const float* __restrict__ W3,
                           u16* __restrict__ hi, u16* __restrict__ lo) {
  int i = blockIdx.x * blockDim.x + threadIdx.x;  // 65536
  int k = i >> 8, j = i & 255;
  float v = (j < 128) ? W2[(k << 7) + j] : W3[(k << 7) + (j - 128)];
  u16 h = f2b(v);
  hi[(size_t)j * 256 + k] = h;
  lo[(size_t)j * 256 + k] = f2b(v - b2f(h));
}

// ---------- CSR build ----------
__global__ void hist_kernel(const int* __restrict__ dst, int* __restrict__ deg) {
  int i = blockIdx.x * blockDim.x + threadIdx.x;
  if (i < NE) atomicAdd(&deg[dst[i]], 1);
}

__global__ void scan_kernel(const int* __restrict__ deg, int* __restrict__ rowptr,
                            int* __restrict__ cursor) {
  __shared__ int sums[1024];
  int t = threadIdx.x;
  int loc[8];
  int s = 0;
#pragma unroll
  for (int j = 0; j < 8; ++j) { s += deg[t * 8 + j]; loc[j] = s; }
  sums[t] = s;
  __syncthreads();
  for (int off = 1; off < 1024; off <<= 1) {
    int v = (t >= off) ? sums[t - off] : 0;
    __syncthreads();
    sums[t] += v;
    __syncthreads();
  }
  int base = (t > 0) ? sums[t - 1] : 0;
  if (t == 0) rowptr[0] = 0;
#pragma unroll
  for (int j = 0; j < 8; ++j) {
    rowptr[t * 8 + j + 1] = base + loc[j];
    cursor[t * 8 + j] = base + (j ? loc[j - 1] : 0);
  }
}

__global__ void scatter_kernel(const int* __restrict__ src, const int* __restrict__ dst,
                               const float* __restrict__ w, int* cursor,
                               int* __restrict__ csr_src, float* __restrict__ csr_w) {
  int i = blockIdx.x * blockDim.x + threadIdx.x;
  if (i >= NE) return;
  int d = dst[i];
  int p = atomicAdd(&cursor[d], 1);
  csr_src[p] = src[i];
  csr_w[p] = w[i];
}

// ---------- split GEMM: C = A(MxK)@B(KxN) f32 out; B packed col-major ----------
// block 256 / 4 waves; wave = 16 rows x 64 cols; grid (M/64, N/64)
__global__ void gemm_split_kernel(const u16* __restrict__ Ah, const u16* __restrict__ Al,
                                  const u16* __restrict__ Bh, const u16* __restrict__ Bl,
                                  float* __restrict__ C, int M, int N, int K) {
  int wave = threadIdx.x >> 6, lane = threadIdx.x & 63;
  int r = lane & 15, kf = (lane >> 4) * 8;
  int row = blockIdx.x * 64 + wave * 16 + r;
  int col0 = blockIdx.y * 64;
  f32x4 acc[4] = {};
  for (int k0 = 0; k0 < K; k0 += 32) {
    int ka = k0 + kf;
    bf16x8 ah = *(const bf16x8*)(Ah + (size_t)row * K + ka);
    bf16x8 al = *(const bf16x8*)(Al + (size_t)row * K + ka);
#pragma unroll
    for (int t = 0; t < 4; ++t) {
      int col = col0 + t * 16 + r;
      bf16x8 bh = *(const bf16x8*)(Bh + (size_t)col * K + ka);
      bf16x8 bl = *(const bf16x8*)(Bl + (size_t)col * K + ka);
      acc[t] = __builtin_amdgcn_mfma_f32_16x16x32_bf16(ah, bh, acc[t], 0, 0, 0);
      acc[t] = __builtin_amdgcn_mfma_f32_16x16x32_bf16(al, bh, acc[t], 0, 0, 0);
      acc[t] = __builtin_amdgcn_mfma_f32_16x16x32_bf16(ah, bl, acc[t], 0, 0, 0);
    }
  }
  int orow = blockIdx.x * 64 + wave * 16 + (lane >> 4) * 4;
#pragma unroll
  for (int t = 0; t < 4; ++t)
#pragma unroll
    for (int q = 0; q < 4; ++q)
      C[(size_t)(orow + q) * N + col0 + t * 16 + r] = acc[t][q];
}

// ---------- spmm (CSR): 4 nodes/block, 64 lanes/node, float4 gather ----------
__global__ void spmm_relu_kernel(const int* __restrict__ rowptr, const int* __restrict__ csr_src,
                                 const float* __restrict__ csr_w, const float* __restrict__ h,
                                 u16* __restrict__ oh, u16* __restrict__ ol) {
  int n = blockIdx.x * 4 + (threadIdx.x >> 6);
  int c = (threadIdx.x & 63) * 4;
  int e0 = rowptr[n], e1 = rowptr[n + 1];
  f32x4 acc = {};
  int i = e0;
  for (; i + 2 <= e1; i += 2) {
    int s0 = csr_src[i], s1 = csr_src[i + 1];
    float w0 = csr_w[i], w1 = csr_w[i + 1];
    f32x4 v0 = *(const f32x4*)(h + (size_t)s0 * 256 + c);
    f32x4 v1 = *(const f32x4*)(h + (size_t)s1 * 256 + c);
#pragma unroll
    for (int j = 0; j < 4; ++j)
      acc[j] = fmaf(w1, v1[j], fmaf(w0, v0[j], acc[j]));
  }
  if (i < e1) {
    float w0 = csr_w[i];
    f32x4 v0 = *(const f32x4*)(h + (size_t)csr_src[i] * 256 + c);
#pragma unroll
    for (int j = 0; j < 4; ++j) acc[j] = fmaf(w0, v0[j], acc[j]);
  }
  u16x4 vh, vl;
#pragma unroll
  for (int j = 0; j < 4; ++j) {
    float a = fmaxf(acc[j], 0.f);
    u16 hb = f2b(a);
    vh[j] = hb;
    vl[j] = f2b(a - b2f(hb));
  }
  *(u16x4*)(oh + (size_t)n * 256 + c) = vh;
  *(u16x4*)(ol + (size_t)n * 256 + c) = vl;
}

__global__ void spmm_out_kernel(const int* __restrict__ rowptr, const int* __restrict__ csr_src,
                                const float* __restrict__ csr_w, const float* __restrict__ h,
                                float* __restrict__ mu, float* __restrict__ logvar,
                                float* __restrict__ z, u16* __restrict__ zb) {
  int n = blockIdx.x * 4 + (threadIdx.x >> 6);
  int c = (threadIdx.x & 63) * 4;
  int e0 = rowptr[n], e1 = rowptr[n + 1];
  f32x4 acc = {};
  int i = e0;
  for (; i + 2 <= e1; i += 2) {
    int s0 = csr_src[i], s1 = csr_src[i + 1];
    float w0 = csr_w[i], w1 = csr_w[i + 1];
    f32x4 v0 = *(const f32x4*)(h + (size_t)s0 * 256 + c);
    f32x4 v1 = *(const f32x4*)(h + (size_t)s1 * 256 + c);
#pragma unroll
    for (int j = 0; j < 4; ++j)
      acc[j] = fmaf(w1, v1[j], fmaf(w0, v0[j], acc[j]));
  }
  if (i < e1) {
    float w0 = csr_w[i];
    f32x4 v0 = *(const f32x4*)(h + (size_t)csr_src[i] * 256 + c);
#pragma unroll
    for (int j = 0; j < 4; ++j) acc[j] = fmaf(w0, v0[j], acc[j]);
  }
  if (c < 128) {
    *(f32x4*)(mu + (size_t)n * 128 + c) = acc;
    *(f32x4*)(z + (size_t)n * 128 + c) = acc;
    u16x4 vb;
#pragma unroll
    for (int j = 0; j < 4; ++j) vb[j] = f2b(acc[j]);
    *(u16x4*)(zb + (size_t)n * 128 + c) = vb;
  } else {
    *(f32x4*)(logvar + (size_t)n * 128 + (c - 128)) = acc;
  }
}

// ---------- adj = Z @ Z^T, Z [8192][128] bf16 ----------
// LDS-staged: tile 128x128, K=128 fully resident. 256 thr / 4 waves;
// wave = 32 rows x 128 cols. XOR-swizzle (row&15)<<4 on the 256B rows kills
// the stride-256B 32-way bank conflict. grid (64 cols, 64 rows).
__global__ void zzt_kernel(const u16* __restrict__ Z, float* __restrict__ C) {
  __shared__ u16 lA[128 * 128];   // 32KB swizzled
  __shared__ u16 lB[128 * 128];   // 32KB swizzled
  int t = threadIdx.x;
  int i0 = blockIdx.y * 128;
  int j0 = blockIdx.x * 128;
  const char* gA = (const char*)(Z + (size_t)i0 * 128);
  const char* gB = (const char*)(Z + (size_t)j0 * 128);
#pragma unroll
  for (int cix = 0; cix < 8; ++cix) {
    int p = (cix * 256 + t) * 16;        // byte offset within 32KB region
    int row = p >> 8;                    // 256B per Z row
    int sw = (p & 255) ^ ((row & 15) << 4);
    bf16x8 va = *(const bf16x8*)(gA + p);
    bf16x8 vb = *(const bf16x8*)(gB + p);
    *(bf16x8*)((char*)lA + row * 256 + sw) = va;
    *(bf16x8*)((char*)lB + row * 256 + sw) = vb;
  }
  __syncthreads();
  int wave = t >> 6, lane = t & 63;
  int lrow = lane & 31;
  int arow = wave * 32 + lrow;
  int aswz = (arow & 15) << 4;
  f32x16 acc[4] = {};
#pragma unroll
  for (int k0 = 0; k0 < 128; k0 += 16) {
    int kb = k0 * 2 + (lane >> 5) * 16;  // byte offset within row
    bf16x8 a = *(const bf16x8*)((const char*)lA + arow * 256 + (kb ^ aswz));
#pragma unroll
    for (int tt = 0; tt < 4; ++tt) {
      int brow = tt * 32 + lrow;
      bf16x8 b = *(const bf16x8*)((const char*)lB + brow * 256 + (kb ^ ((brow & 15) << 4)));
      acc[tt] = __builtin_amdgcn_mfma_f32_32x32x16_bf16(a, b, acc[tt], 0, 0, 0);
    }
  }
  int rb = wave * 32 + 4 * (lane >> 5);
  int col = lane & 31;
#pragma unroll
  for (int tt = 0; tt < 4; ++tt) {
#pragma unroll
    for (int reg = 0; reg < 16; ++reg) {
      int rr = rb + (reg & 3) + 8 * (reg >> 2);
      __builtin_nontemporal_store(acc[tt][reg],
          &C[(size_t)(i0 + rr) * NN + j0 + tt * 32 + col]);
    }
  }
}

extern "C" void kernel_launch(void* const* d_in, const int* in_sizes, int n_in,
                              void* d_out, int out_size, void* d_ws, size_t ws_size,
                              hipStream_t stream) {
  const float* x  = (const float*)d_in[0];
  const int*   ei = (const int*)d_in[1];
  const float* ew = (const float*)d_in[2];
  const float* W1 = (const float*)d_in[3];
  const float* W2 = (const float*)d_in[4];
  const float* W3 = (const float*)d_in[5];

  float* out    = (float*)d_out;
  float* adj    = out;                                   // [8192,8192]
  float* mu     = out + (size_t)NN * NN;                 // [8192,128]
  float* logv   = mu + (size_t)NN * 128;                 // [8192,128]
  float* z      = logv + (size_t)NN * 128;               // [8192,128]

  const int* srcp = ei;
  const int* dstp = ei + NE;

  char* ws = (char*)d_ws;
  size_t off = 0;
  auto alloc = [&](size_t b) -> void* {
    void* p = ws + off;
    off = (off + b + 255) & ~(size_t)255;
    return p;
  };
  u16* xh   = (u16*)alloc((size_t)NN * 512 * 2);
  u16* xl   = (u16*)alloc((size_t)NN * 512 * 2);
  u16* W1h  = (u16*)alloc(512 * 256 * 2);   // col-major [256][512]
  u16* W1l  = (u16*)alloc(512 * 256 * 2);
  u16* W23h = (u16*)alloc(256 * 256 * 2);   // col-major [256][256]
  u16* W23l = (u16*)alloc(256 * 256 * 2);
  float* h0 = (float*)alloc((size_t)NN * 256 * 4);
  u16* h1h  = (u16*)alloc((size_t)NN * 256 * 2);
  u16* h1l  = (u16*)alloc((size_t)NN * 256 * 2);
  float* H2 = (float*)alloc((size_t)NN * 256 * 4);
  u16* zb   = (u16*)alloc((size_t)NN * 128 * 2);
  int* deg      = (int*)alloc(NN * 4);
  int* rowptr   = (int*)alloc((NN + 1) * 4);
  int* cursor   = (int*)alloc(NN * 4);
  int* csr_src  = (int*)alloc((size_t)NE * 4);
  float* csr_w  = (float*)alloc((size_t)NE * 4);

  hipMemsetAsync(deg, 0, NN * 4, stream);

  // converts
  split_x<<<(NN * 512 / 4) / 256, 256, 0, stream>>>(x, xh, xl);
  splitT_w1<<<(512 * 256) / 256, 256, 0, stream>>>(W1, W1h, W1l);
  build_w23T<<<(256 * 256) / 256, 256, 0, stream>>>(W2, W3, W23h, W23l);

  // CSR build
  hist_kernel<<<NE / 256, 256, 0, stream>>>(dstp, deg);
  scan_kernel<<<1, 1024, 0, stream>>>(deg, rowptr, cursor);
  scatter_kernel<<<NE / 256, 256, 0, stream>>>(srcp, dstp, ew, cursor, csr_src, csr_w);

  // h0 = x @ W1 (f32)
  gemm_split_kernel<<<dim3(NN / 64, 256 / 64), 256, 0, stream>>>(xh, xl, W1h, W1l, h0,
                                                                 NN, 256, 512);
  // h1 = relu(spmm(h0)) -> split hi/lo
  spmm_relu_kernel<<<NN / 4, 256, 0, stream>>>(rowptr, csr_src, csr_w, h0, h1h, h1l);
  // H2 = h1 @ [W2|W3] (f32)
  gemm_split_kernel<<<dim3(NN / 64, 256 / 64), 256, 0, stream>>>(h1h, h1l, W23h, W23l, H2,
                                                                 NN, 256, 256);
  // mu/logvar = spmm(H2); z = mu; zb = bf16(mu)
  spmm_out_kernel<<<NN / 4, 256, 0, stream>>>(rowptr, csr_src, csr_w, H2, mu, logv, z, zb);
  // adj = z @ z^T  (LDS-staged, swizzled)
  zzt_kernel<<<dim3(NN / 128, NN / 128), 256, 0, stream>>>(zb, adj);
}

// Round 7
// 219.566 us; speedup vs baseline: 1.5812x; 1.0070x over previous
//
#include <hip/hip_runtime.h>
#include <hip/hip_bf16.h>

#define NN 8192
#define NE 262144

typedef __attribute__((ext_vector_type(8))) short bf16x8;
typedef __attribute__((ext_vector_type(4))) float f32x4;
typedef __attribute__((ext_vector_type(16))) float f32x16;
typedef unsigned short u16;
typedef __attribute__((ext_vector_type(4))) u16 u16x4;

__device__ inline u16 f2b(float f) {
  unsigned u = __float_as_uint(f);
  unsigned r = u + 0x7FFF + ((u >> 16) & 1);   // RNE to bf16
  return (u16)(r >> 16);
}
__device__ inline float b2f(u16 b) {
  return __uint_as_float(((unsigned)b) << 16);
}

// ---------- converts ----------
__global__ void split_x(const float* __restrict__ in, u16* __restrict__ hi,
                        u16* __restrict__ lo) {
  int i = (blockIdx.x * blockDim.x + threadIdx.x) * 4;
  f32x4 v = *(const f32x4*)(in + i);
  u16x4 vh, vl;
#pragma unroll
  for (int j = 0; j < 4; ++j) {
    u16 h = f2b(v[j]);
    vh[j] = h;
    vl[j] = f2b(v[j] - b2f(h));
  }
  *(u16x4*)(hi + i) = vh;
  *(u16x4*)(lo + i) = vl;
}

// W1 [512][256] row-major -> col-major [256][512] hi/lo
__global__ void splitT_w1(const float* __restrict__ in, u16* __restrict__ hi,
                          u16* __restrict__ lo) {
  int i = blockIdx.x * blockDim.x + threadIdx.x;  // 512*256
  int k = i >> 8, n = i & 255;
  float v = in[i];
  u16 h = f2b(v);
  hi[(size_t)n * 512 + k] = h;
  lo[(size_t)n * 512 + k] = f2b(v - b2f(h));
}

// W23 col-major [256 cols][256 k]: col j<128 = W2[:,j], j>=128 = W3[:,j-128]
__global__ void build_w23T(const float* __restrict__ W2, const float* __restrict__ W3,
                           u16* __restrict__ hi, u16* __restrict__ lo) {
  int i = blockIdx.x * blockDim.x + threadIdx.x;  // 65536
  int k = i >> 8, j = i & 255;
  float v = (j < 128) ? W2[(k << 7) + j] : W3[(k << 7) + (j - 128)];
  u16 h = f2b(v);
  hi[(size_t)j * 256 + k] = h;
  lo[(size_t)j * 256 + k] = f2b(v - b2f(h));
}

// ---------- CSR build ----------
__global__ void hist_kernel(const int* __restrict__ dst, int* __restrict__ deg) {
  int i = blockIdx.x * blockDim.x + threadIdx.x;
  if (i < NE) atomicAdd(&deg[dst[i]], 1);
}

__global__ void scan_kernel(const int* __restrict__ deg, int* __restrict__ rowptr,
                            int* __restrict__ cursor) {
  __shared__ int sums[1024];
  int t = threadIdx.x;
  int loc[8];
  int s = 0;
#pragma unroll
  for (int j = 0; j < 8; ++j) { s += deg[t * 8 + j]; loc[j] = s; }
  sums[t] = s;
  __syncthreads();
  for (int off = 1; off < 1024; off <<= 1) {
    int v = (t >= off) ? sums[t - off] : 0;
    __syncthreads();
    sums[t] += v;
    __syncthreads();
  }
  int base = (t > 0) ? sums[t - 1] : 0;
  if (t == 0) rowptr[0] = 0;
#pragma unroll
  for (int j = 0; j < 8; ++j) {
    rowptr[t * 8 + j + 1] = base + loc[j];
    cursor[t * 8 + j] = base + (j ? loc[j - 1] : 0);
  }
}

__global__ void scatter_kernel(const int* __restrict__ src, const int* __restrict__ dst,
                               const float* __restrict__ w, int* cursor,
                               int* __restrict__ csr_src, float* __restrict__ csr_w) {
  int i = blockIdx.x * blockDim.x + threadIdx.x;
  if (i >= NE) return;
  int d = dst[i];
  int p = atomicAdd(&cursor[d], 1);
  csr_src[p] = src[i];
  csr_w[p] = w[i];
}

// ---------- split GEMM: C = A(MxK)@B(KxN) f32 out; B packed col-major ----------
// block 256 / 4 waves; wave = 16 rows x 64 cols; grid (M/64, N/64)
__global__ void gemm_split_kernel(const u16* __restrict__ Ah, const u16* __restrict__ Al,
                                  const u16* __restrict__ Bh, const u16* __restrict__ Bl,
                                  float* __restrict__ C, int M, int N, int K) {
  int wave = threadIdx.x >> 6, lane = threadIdx.x & 63;
  int r = lane & 15, kf = (lane >> 4) * 8;
  int row = blockIdx.x * 64 + wave * 16 + r;
  int col0 = blockIdx.y * 64;
  f32x4 acc[4] = {};
  for (int k0 = 0; k0 < K; k0 += 32) {
    int ka = k0 + kf;
    bf16x8 ah = *(const bf16x8*)(Ah + (size_t)row * K + ka);
    bf16x8 al = *(const bf16x8*)(Al + (size_t)row * K + ka);
#pragma unroll
    for (int t = 0; t < 4; ++t) {
      int col = col0 + t * 16 + r;
      bf16x8 bh = *(const bf16x8*)(Bh + (size_t)col * K + ka);
      bf16x8 bl = *(const bf16x8*)(Bl + (size_t)col * K + ka);
      acc[t] = __builtin_amdgcn_mfma_f32_16x16x32_bf16(ah, bh, acc[t], 0, 0, 0);
      acc[t] = __builtin_amdgcn_mfma_f32_16x16x32_bf16(al, bh, acc[t], 0, 0, 0);
      acc[t] = __builtin_amdgcn_mfma_f32_16x16x32_bf16(ah, bl, acc[t], 0, 0, 0);
    }
  }
  int orow = blockIdx.x * 64 + wave * 16 + (lane >> 4) * 4;
#pragma unroll
  for (int t = 0; t < 4; ++t)
#pragma unroll
    for (int q = 0; q < 4; ++q)
      C[(size_t)(orow + q) * N + col0 + t * 16 + r] = acc[t][q];
}

// ---------- spmm (CSR): 4 nodes/block, 64 lanes/node, float4 gather ----------
__global__ void spmm_relu_kernel(const int* __restrict__ rowptr, const int* __restrict__ csr_src,
                                 const float* __restrict__ csr_w, const float* __restrict__ h,
                                 u16* __restrict__ oh, u16* __restrict__ ol) {
  int n = blockIdx.x * 4 + (threadIdx.x >> 6);
  int c = (threadIdx.x & 63) * 4;
  int e0 = rowptr[n], e1 = rowptr[n + 1];
  f32x4 acc = {};
  int i = e0;
  for (; i + 2 <= e1; i += 2) {
    int s0 = csr_src[i], s1 = csr_src[i + 1];
    float w0 = csr_w[i], w1 = csr_w[i + 1];
    f32x4 v0 = *(const f32x4*)(h + (size_t)s0 * 256 + c);
    f32x4 v1 = *(const f32x4*)(h + (size_t)s1 * 256 + c);
#pragma unroll
    for (int j = 0; j < 4; ++j)
      acc[j] = fmaf(w1, v1[j], fmaf(w0, v0[j], acc[j]));
  }
  if (i < e1) {
    float w0 = csr_w[i];
    f32x4 v0 = *(const f32x4*)(h + (size_t)csr_src[i] * 256 + c);
#pragma unroll
    for (int j = 0; j < 4; ++j) acc[j] = fmaf(w0, v0[j], acc[j]);
  }
  u16x4 vh, vl;
#pragma unroll
  for (int j = 0; j < 4; ++j) {
    float a = fmaxf(acc[j], 0.f);
    u16 hb = f2b(a);
    vh[j] = hb;
    vl[j] = f2b(a - b2f(hb));
  }
  *(u16x4*)(oh + (size_t)n * 256 + c) = vh;
  *(u16x4*)(ol + (size_t)n * 256 + c) = vl;
}

__global__ void spmm_out_kernel(const int* __restrict__ rowptr, const int* __restrict__ csr_src,
                                const float* __restrict__ csr_w, const float* __restrict__ h,
                                float* __restrict__ mu, float* __restrict__ logvar,
                                float* __restrict__ z, u16* __restrict__ zb) {
  int n = blockIdx.x * 4 + (threadIdx.x >> 6);
  int c = (threadIdx.x & 63) * 4;
  int e0 = rowptr[n], e1 = rowptr[n + 1];
  f32x4 acc = {};
  int i = e0;
  for (; i + 2 <= e1; i += 2) {
    int s0 = csr_src[i], s1 = csr_src[i + 1];
    float w0 = csr_w[i], w1 = csr_w[i + 1];
    f32x4 v0 = *(const f32x4*)(h + (size_t)s0 * 256 + c);
    f32x4 v1 = *(const f32x4*)(h + (size_t)s1 * 256 + c);
#pragma unroll
    for (int j = 0; j < 4; ++j)
      acc[j] = fmaf(w1, v1[j], fmaf(w0, v0[j], acc[j]));
  }
  if (i < e1) {
    float w0 = csr_w[i];
    f32x4 v0 = *(const f32x4*)(h + (size_t)csr_src[i] * 256 + c);
#pragma unroll
    for (int j = 0; j < 4; ++j) acc[j] = fmaf(w0, v0[j], acc[j]);
  }
  if (c < 128) {
    *(f32x4*)(mu + (size_t)n * 128 + c) = acc;
    *(f32x4*)(z + (size_t)n * 128 + c) = acc;
    u16x4 vb;
#pragma unroll
    for (int j = 0; j < 4; ++j) vb[j] = f2b(acc[j]);
    *(u16x4*)(zb + (size_t)n * 128 + c) = vb;
  } else {
    *(f32x4*)(logvar + (size_t)n * 128 + (c - 128)) = acc;
  }
}

// ---------- adj = Z @ Z^T, Z [8192][128] bf16 ----------
// v3b: A in registers (wave-private rows), B in 32KB swizzled LDS -> 4 blocks/CU.
// block 256 / 4 waves; tile 128x128; wave = 32 rows x 128 cols; grid (64,64).
__global__ void zzt_kernel(const u16* __restrict__ Z, float* __restrict__ C) {
  __shared__ u16 lB[128 * 128];   // 32KB swizzled (rows = C cols)
  int t = threadIdx.x;
  int i0 = blockIdx.y * 128;
  int j0 = blockIdx.x * 128;
  // stage B: 32KB = 8 chunks x 256 threads x 16B, sequential + swizzled write
  const char* gB = (const char*)(Z + (size_t)j0 * 128);
#pragma unroll
  for (int cix = 0; cix < 8; ++cix) {
    int p = (cix * 256 + t) * 16;
    int row = p >> 8;
    int sw = (p & 255) ^ ((row & 15) << 4);
    bf16x8 vb = *(const bf16x8*)(gB + p);
    *(bf16x8*)((char*)lB + row * 256 + sw) = vb;
  }
  // A in registers: lane holds its MFMA A-fragment rows directly
  int wave = t >> 6, lane = t & 63;
  int lrow = lane & 31, hi = lane >> 5;
  const u16* aRow = Z + (size_t)(i0 + wave * 32 + lrow) * 128 + hi * 8;
  bf16x8 a[8];
#pragma unroll
  for (int k = 0; k < 8; ++k)
    a[k] = *(const bf16x8*)(aRow + k * 16);
  __syncthreads();
  f32x16 acc[4] = {};
#pragma unroll
  for (int ks = 0; ks < 8; ++ks) {
    int kb = ks * 32 + hi * 16;          // byte offset within 256B row
#pragma unroll
    for (int tt = 0; tt < 4; ++tt) {
      int brow = tt * 32 + lrow;
      bf16x8 b = *(const bf16x8*)((const char*)lB + brow * 256 + (kb ^ ((brow & 15) << 4)));
      acc[tt] = __builtin_amdgcn_mfma_f32_32x32x16_bf16(a[ks], b, acc[tt], 0, 0, 0);
    }
  }
  int rb = wave * 32 + 4 * (lane >> 5);
  int col = lane & 31;
#pragma unroll
  for (int tt = 0; tt < 4; ++tt) {
#pragma unroll
    for (int reg = 0; reg < 16; ++reg) {
      int rr = rb + (reg & 3) + 8 * (reg >> 2);
      __builtin_nontemporal_store(acc[tt][reg],
          &C[(size_t)(i0 + rr) * NN + j0 + tt * 32 + col]);
    }
  }
}

extern "C" void kernel_launch(void* const* d_in, const int* in_sizes, int n_in,
                              void* d_out, int out_size, void* d_ws, size_t ws_size,
                              hipStream_t stream) {
  const float* x  = (const float*)d_in[0];
  const int*   ei = (const int*)d_in[1];
  const float* ew = (const float*)d_in[2];
  const float* W1 = (const float*)d_in[3];
  const float* W2 = (const float*)d_in[4];
  const float* W3 = (const float*)d_in[5];

  float* out    = (float*)d_out;
  float* adj    = out;                                   // [8192,8192]
  float* mu     = out + (size_t)NN * NN;                 // [8192,128]
  float* logv   = mu + (size_t)NN * 128;                 // [8192,128]
  float* z      = logv + (size_t)NN * 128;               // [8192,128]

  const int* srcp = ei;
  const int* dstp = ei + NE;

  char* ws = (char*)d_ws;
  size_t off = 0;
  auto alloc = [&](size_t b) -> void* {
    void* p = ws + off;
    off = (off + b + 255) & ~(size_t)255;
    return p;
  };
  u16* xh   = (u16*)alloc((size_t)NN * 512 * 2);
  u16* xl   = (u16*)alloc((size_t)NN * 512 * 2);
  u16* W1h  = (u16*)alloc(512 * 256 * 2);   // col-major [256][512]
  u16* W1l  = (u16*)alloc(512 * 256 * 2);
  u16* W23h = (u16*)alloc(256 * 256 * 2);   // col-major [256][256]
  u16* W23l = (u16*)alloc(256 * 256 * 2);
  float* h0 = (float*)alloc((size_t)NN * 256 * 4);
  u16* h1h  = (u16*)alloc((size_t)NN * 256 * 2);
  u16* h1l  = (u16*)alloc((size_t)NN * 256 * 2);
  float* H2 = (float*)alloc((size_t)NN * 256 * 4);
  u16* zb   = (u16*)alloc((size_t)NN * 128 * 2);
  int* deg      = (int*)alloc(NN * 4);
  int* rowptr   = (int*)alloc((NN + 1) * 4);
  int* cursor   = (int*)alloc(NN * 4);
  int* csr_src  = (int*)alloc((size_t)NE * 4);
  float* csr_w  = (float*)alloc((size_t)NE * 4);

  hipMemsetAsync(deg, 0, NN * 4, stream);

  // converts
  split_x<<<(NN * 512 / 4) / 256, 256, 0, stream>>>(x, xh, xl);
  splitT_w1<<<(512 * 256) / 256, 256, 0, stream>>>(W1, W1h, W1l);
  build_w23T<<<(256 * 256) / 256, 256, 0, stream>>>(W2, W3, W23h, W23l);

  // CSR build
  hist_kernel<<<NE / 256, 256, 0, stream>>>(dstp, deg);
  scan_kernel<<<1, 1024, 0, stream>>>(deg, rowptr, cursor);
  scatter_kernel<<<NE / 256, 256, 0, stream>>>(srcp, dstp, ew, cursor, csr_src, csr_w);

  // h0 = x @ W1 (f32)
  gemm_split_kernel<<<dim3(NN / 64, 256 / 64), 256, 0, stream>>>(xh, xl, W1h, W1l, h0,
                                                                 NN, 256, 512);
  // h1 = relu(spmm(h0)) -> split hi/lo
  spmm_relu_kernel<<<NN / 4, 256, 0, stream>>>(rowptr, csr_src, csr_w, h0, h1h, h1l);
  // H2 = h1 @ [W2|W3] (f32)
  gemm_split_kernel<<<dim3(NN / 64, 256 / 64), 256, 0, stream>>>(h1h, h1l, W23h, W23l, H2,
                                                                 NN, 256, 256);
  // mu/logvar = spmm(H2); z = mu; zb = bf16(mu)
  spmm_out_kernel<<<NN / 4, 256, 0, stream>>>(rowptr, csr_src, csr_w, H2, mu, logv, z, zb);
  // adj = z @ z^T  (A-in-reg, B-in-LDS, 4 blocks/CU)
  zzt_kernel<<<dim3(NN / 128, NN / 128), 256, 0, stream>>>(zb, adj);
}